// Round 3
// baseline (200.561 us; speedup 1.0000x reference)
//
#include <hip/hip_runtime.h>
#include <hip/hip_fp16.h>

// TrigHashGrid: B=1048576, IN_DIM=3, M=3, N=16, C=2, W=1000, A=-0.75
// R7: DIAGNOSTIC PROBE. R5 (occupancy 2x) bought only 21%; R6 (x prefetch +
// fp16 LDS taps) was neutral. Models say ~22-25us floor; kernel sits ~70us
// with no pipe >30% busy (per last visible counters, R4). Since R5 the
// kernel runs below the harness's ~80-84us fillBuffer re-poison dispatches
// and fell out of rocprof's top-5 -- flying blind. This round: identical R6
// body, but 22 inner iterations instead of 16 (iters 16..21 replay strides
// 0..5, overwriting identical values -> bitwise-identical output). Kernel
// time ~x1.375 ~= 96us > fills -> full PMC row becomes visible.
// Decision table on the counters (divide by 1.375 vs R4):
//   VGPR==64            -> register-pressure/spill is the story
//   Occupancy <=40%     -> 2-blocks/CU residency never happened
//   VALUBusy >=55%      -> VALU diet (pk_fma interp) is the lever
//   conflicts ~13M flat -> random LDS reads mispriced; restructure taps

constexpr int B_TOT = 1048576;
constexpr float A_C = -0.75f;

#define BLK 1024
#define WPAD 1004            // 2 + 1000 + 2 positions, one __half2 each

__device__ __forceinline__ float hw_sin(float a) {
    // sin(a) = v_sin_f32(fract(a / 2pi)); v_fract wraps negatives correctly.
    float rev = a * 0.15915494309189535f;
    rev = __builtin_amdgcn_fractf(rev);
    return __builtin_amdgcn_sinf(rev);
}

__global__ __launch_bounds__(BLK, 8)
void trig_hashgrid(const float* __restrict__ x, const float* __restrict__ grids,
                   const float* __restrict__ G, const float* __restrict__ H,
                   float* __restrict__ out)
{
    __shared__ __half2 lds[8 * WPAD];         // 32128 B
    const int tid  = threadIdx.x;
    const int half = blockIdx.x & 1;          // which 8 of the 16 levels
    const int blk  = blockIdx.x >> 1;         // 0..511

    // Zero the 4 pad positions per level row (padded w {0,1,1002,1003}).
    if (tid < 32) {
        int nl = tid >> 2, j = tid & 3;
        int off = (j < 2) ? j : (WPAD - 4 + j);
        lds[nl * WPAD + off] = __floats2half2_rn(0.0f, 0.0f);
    }
    // Stage grids[half*8 .. half*8+8) as packed half2(c0,c1) per w position.
    {
        int row = tid >> 7;                   // 0..7 (level within half)
        int j   = tid & 127;
        const float* gsrc = grids + half * 16000 + row * 2000;
        __half2* ldst = lds + row * WPAD;
        for (int w = j; w < 1000; w += 128)
            ldst[w + 2] = __floats2half2_rn(gsrc[w], gsrc[1000 + w]);
    }

    const int n_loc = tid & 7;
    const int n     = half * 8 + n_loc;       // fixed per thread
    const int g     = tid >> 3;               // 0..127

    // Per-level frequencies/phases in registers (reused all iters).
    float G0[3], G1[3], G2[3], Hr[3];
#pragma unroll
    for (int m = 0; m < 3; ++m) {
        G0[m] = G[0 * 48 + m * 16 + n];
        G1[m] = G[1 * 48 + m * 16 + n];
        G2[m] = G[2 * 48 + m * 16 + n];
        Hr[m] = H[m * 16 + n];
    }
    __syncthreads();

    float2* __restrict__ out2 = (float2*)out;
    const __half2* lrow = &lds[n_loc * WPAD];

    // DIAGNOSTIC: rep 0 = the real 16 iterations; rep 1 replays strides 0..5
    // (identical recompute, overwrites same outputs) purely to push the
    // dispatch above the ~84us fillBuffer dispatches so rocprof shows PMC.
    for (int rep = 0; rep < 2; ++rep) {
        const int iters = rep ? 6 : 16;
        int b = blk * 128 + g;
        float x0 = x[b * 3 + 0];
        float x1 = x[b * 3 + 1];
        float x2 = x[b * 3 + 2];

#pragma unroll 2
        for (int i = 0; i < iters; ++i) {
            const int bn = b + 512 * 128;
            const int bs = (i < iters - 1) ? bn : b;  // clamp: no OOB read
            float y0 = x[bs * 3 + 0];                 // next iter's x, early
            float y1 = x[bs * 3 + 1];
            float y2 = x[bs * 3 + 2];

            float p = 1.0f;
#pragma unroll
            for (int m = 0; m < 3; ++m) {
                float a = fmaf(x0, G0[m], fmaf(x1, G1[m], fmaf(x2, G2[m], Hr[m])));
                p *= hw_sin(a);
            }

            float ix = fmaf(p, 500.0f, 499.5f);       // [-0.5, 999.5]
            float xf = floorf(ix);
            float t  = ix - xf;
            int base = (int)xf;                       // [-1, 999]
            base = min(max(base, -1), 999);           // cheap insurance

            // Factored Keys weights.
            float u   = 1.0f - t;
            float tu  = t * u;
            float atu = A_C * tu;
            float w0  = atu * u;
            float w3  = atu * t;
            float w1  = fmaf(fmaf(A_C + 2.0f, t, -(A_C + 3.0f)), t * t, 1.0f);
            float w2  = 1.0f - w0 - w1 - w3;

            // 4 consecutive padded taps starting at padded index base+1 >= 0.
            const __half2* tap = lrow + (base + 1);
            float2 v0 = __half22float2(tap[0]);
            float2 v1 = __half22float2(tap[1]);
            float2 v2 = __half22float2(tap[2]);
            float2 v3 = __half22float2(tap[3]);

            float o0 = v0.x * w0, o1 = v0.y * w0;
            o0 = fmaf(v1.x, w1, o0); o1 = fmaf(v1.y, w1, o1);
            o0 = fmaf(v2.x, w2, o0); o1 = fmaf(v2.y, w2, o1);
            o0 = fmaf(v3.x, w3, o0); o1 = fmaf(v3.y, w3, o1);

            // out[b, n, c] flat -> float2 at b*16 + n.
            out2[b * 16 + n] = make_float2(o0, o1);

            b = bn; x0 = y0; x1 = y1; x2 = y2;
        }
    }
}

extern "C" void kernel_launch(void* const* d_in, const int* in_sizes, int n_in,
                              void* d_out, int out_size, void* d_ws, size_t ws_size,
                              hipStream_t stream) {
    const float* x     = (const float*)d_in[0];
    const float* grids = (const float*)d_in[1];
    const float* G     = (const float*)d_in[2];
    const float* H     = (const float*)d_in[3];
    float* out = (float*)d_out;
    trig_hashgrid<<<1024, BLK, 0, stream>>>(x, grids, G, H, out);
}

// Round 4
// 187.360 us; speedup vs baseline: 1.0705x; 1.0705x over previous
//
#include <hip/hip_runtime.h>
#include <hip/hip_fp16.h>

// TrigHashGrid: B=1048576, IN_DIM=3, M=3, N=16, C=2, W=1000, A=-0.75
// R8: tap software-pipeline. R7 probe: VGPR=28, Occupancy 61%, VALUBusy 38%,
// LDS pipe ~28% (fp16 halved conflicts but time flat) -- nothing saturated.
// => per-wave chain stall: sin -> data-dep addr -> 4x ds_read -> lgkmcnt(0)
// drain -> interp. Fix: depth-1 pipeline of the taps. Per iter: compute
// stage i+1 (sins/weights/tap ptr) from prefetched x, ISSUE its 4 ds_reads,
// prefetch x_{i+2}, THEN consume stage i's taps (counted lgkmcnt(4) leaves
// set i+1 in flight) and store. LDS latency hides under interp+next sin
// chain. Secondary: packed-fp16 interp (4x v_pk_fma_f16 + 4x cvt_pkrtz)
// replaces 8 f32 FMA + 8 cvt. ~+15 VGPR (28->~45, <=64 so 8 waves/SIMD
// holds). fp16 accum error <= ~2e-3 worst on 0.0039 base, thr 8.87e-3.

constexpr float A_C = -0.75f;

#define BLK 1024
#define WPAD 1004            // 2 + 1000 + 2 positions, one __half2 each

__device__ __forceinline__ float hw_sin(float a) {
    // sin(a) = v_sin_f32(fract(a / 2pi)); v_fract wraps negatives correctly.
    float rev = a * 0.15915494309189535f;
    rev = __builtin_amdgcn_fractf(rev);
    return __builtin_amdgcn_sinf(rev);
}

// Compute one iteration's interpolation stage: packed fp16 weights + tap ptr.
__device__ __forceinline__ void make_stage(
    float x0, float x1, float x2,
    const float G0[3], const float G1[3], const float G2[3], const float Hr[3],
    const __half2* lrow,
    __half2& W0, __half2& W1, __half2& W2, __half2& W3,
    const __half2*& tap)
{
    float p = 1.0f;
#pragma unroll
    for (int m = 0; m < 3; ++m) {
        float a = fmaf(x0, G0[m], fmaf(x1, G1[m], fmaf(x2, G2[m], Hr[m])));
        p *= hw_sin(a);
    }
    float ix = fmaf(p, 500.0f, 499.5f);                // [-0.5, 999.5]
    float xf = floorf(ix);
    float t  = ix - xf;
    int base = (int)xf;                                // [-1, 999]
    base = min(max(base, -1), 999);                    // cheap insurance

    // Factored Keys weights:
    // w0 = A t u^2, w3 = A t^2 u, w1 = ((A+2)t-(A+3))t^2+1, w2 = 1-rest
    float u   = 1.0f - t;
    float tu  = t * u;
    float atu = A_C * tu;
    float w0  = atu * u;
    float w3  = atu * t;
    float w1  = fmaf(fmaf(A_C + 2.0f, t, -(A_C + 3.0f)), t * t, 1.0f);
    float w2  = 1.0f - w0 - w1 - w3;

    W0 = __float2half2_rn(w0);                         // broadcast to both ch
    W1 = __float2half2_rn(w1);
    W2 = __float2half2_rn(w2);
    W3 = __float2half2_rn(w3);
    tap = lrow + (base + 1);                           // padded idx >= 0
}

__global__ __launch_bounds__(BLK, 8)
void trig_hashgrid(const float* __restrict__ x, const float* __restrict__ grids,
                   const float* __restrict__ G, const float* __restrict__ H,
                   float* __restrict__ out)
{
    __shared__ __half2 lds[8 * WPAD];         // 32128 B
    const int tid  = threadIdx.x;
    const int half = blockIdx.x & 1;          // which 8 of the 16 levels
    const int blk  = blockIdx.x >> 1;         // 0..511

    // Zero the 4 pad positions per level row (padded w {0,1,1002,1003}).
    if (tid < 32) {
        int nl = tid >> 2, j = tid & 3;
        int off = (j < 2) ? j : (WPAD - 4 + j);
        lds[nl * WPAD + off] = __floats2half2_rn(0.0f, 0.0f);
    }
    // Stage grids[half*8 .. half*8+8) as packed half2(c0,c1) per w position.
    {
        int row = tid >> 7;                   // 0..7 (level within half)
        int j   = tid & 127;
        const float* gsrc = grids + half * 16000 + row * 2000;
        __half2* ldst = lds + row * WPAD;
        for (int w = j; w < 1000; w += 128)
            ldst[w + 2] = __floats2half2_rn(gsrc[w], gsrc[1000 + w]);
    }

    const int n_loc = tid & 7;
    const int n     = half * 8 + n_loc;       // fixed per thread
    const int g     = tid >> 3;               // 0..127

    // Per-level frequencies/phases in registers (reused all iters).
    float G0[3], G1[3], G2[3], Hr[3];
#pragma unroll
    for (int m = 0; m < 3; ++m) {
        G0[m] = G[0 * 48 + m * 16 + n];
        G1[m] = G[1 * 48 + m * 16 + n];
        G2[m] = G[2 * 48 + m * 16 + n];
        Hr[m] = H[m * 16 + n];
    }
    __syncthreads();

    float2* __restrict__ out2 = (float2*)out;
    const __half2* lrow = &lds[n_loc * WPAD];

    // 16 iterations, b stride 65536. Depth-1 pipeline on taps and x.
    int b  = blk * 128 + g;
    int b1 = b + 65536;

    float y0, y1, y2;                          // x for stage i+1
    __half2 W0, W1, W2, W3, t0, t1, t2, t3;    // stage i (weights + taps)
    const __half2* tp;

    {   // prologue: stage 0 + issue its loads + x for iter 1
        float x0 = x[b * 3 + 0], x1 = x[b * 3 + 1], x2 = x[b * 3 + 2];
        make_stage(x0, x1, x2, G0, G1, G2, Hr, lrow, W0, W1, W2, W3, tp);
        t0 = tp[0]; t1 = tp[1]; t2 = tp[2]; t3 = tp[3];
        y0 = x[b1 * 3 + 0]; y1 = x[b1 * 3 + 1]; y2 = x[b1 * 3 + 2];
    }

#pragma unroll 3
    for (int i = 0; i < 15; ++i) {
        // 1. compute stage i+1 from y (overlaps stage-i loads in flight)
        __half2 nW0, nW1, nW2, nW3;
        const __half2* ntp;
        make_stage(y0, y1, y2, G0, G1, G2, Hr, lrow, nW0, nW1, nW2, nW3, ntp);
        // 2. issue stage i+1 tap loads
        __half2 u0 = ntp[0], u1 = ntp[1], u2 = ntp[2], u3 = ntp[3];
        // 3. prefetch x for i+2 (clamped on the tail; redundant re-read ok)
        int b2 = (i < 14) ? b1 + 65536 : b1;
        float z0 = x[b2 * 3 + 0], z1 = x[b2 * 3 + 1], z2 = x[b2 * 3 + 2];
        // 4. consume stage i (counted lgkmcnt leaves set i+1 in flight)
        __half2 acc = __hmul2(t0, W0);
        acc = __hfma2(t1, W1, acc);
        acc = __hfma2(t2, W2, acc);
        acc = __hfma2(t3, W3, acc);
        out2[b * 16 + n] = __half22float2(acc);
        // 5. rotate
        b = b1; b1 = b2;
        y0 = z0; y1 = z1; y2 = z2;
        W0 = nW0; W1 = nW1; W2 = nW2; W3 = nW3;
        t0 = u0;  t1 = u1;  t2 = u2;  t3 = u3;
    }

    {   // epilogue: last interp (stage 15)
        __half2 acc = __hmul2(t0, W0);
        acc = __hfma2(t1, W1, acc);
        acc = __hfma2(t2, W2, acc);
        acc = __hfma2(t3, W3, acc);
        out2[b * 16 + n] = __half22float2(acc);
    }
}

extern "C" void kernel_launch(void* const* d_in, const int* in_sizes, int n_in,
                              void* d_out, int out_size, void* d_ws, size_t ws_size,
                              hipStream_t stream) {
    const float* x     = (const float*)d_in[0];
    const float* grids = (const float*)d_in[1];
    const float* G     = (const float*)d_in[2];
    const float* H     = (const float*)d_in[3];
    float* out = (float*)d_out;
    trig_hashgrid<<<1024, BLK, 0, stream>>>(x, grids, G, H, out);
}